// Round 1
// baseline (8627.168 us; speedup 1.0000x reference)
//
#include <hip/hip_runtime.h>
#include <cstdint>
#include <cstddef>

// ---------------- problem constants ----------------
// B=32, ENC=512, P=196 (14x14), ATT=512, EMB=512, DEC=512, VOCAB=10000, T=63
typedef _Float16 f16;
typedef _Float16 h2 __attribute__((ext_vector_type(2)));
typedef _Float16 h8 __attribute__((ext_vector_type(8)));
typedef float f4v __attribute__((ext_vector_type(4)));

// ---------------- helpers ----------------
__device__ __forceinline__ h2 u2h2(unsigned u) { return __builtin_bit_cast(h2, u); }
__device__ __forceinline__ unsigned h22u(h2 v) { return __builtin_bit_cast(unsigned, v); }
__device__ __forceinline__ float2 u2f2(unsigned long long u) { return __builtin_bit_cast(float2, u); }

__device__ __forceinline__ float agent_ld_f(const float* p) {
    return __hip_atomic_load(p, __ATOMIC_RELAXED, __HIP_MEMORY_SCOPE_AGENT);
}
__device__ __forceinline__ void agent_st_f(float* p, float v) {
    __hip_atomic_store(p, v, __ATOMIC_RELAXED, __HIP_MEMORY_SCOPE_AGENT);
}
__device__ __forceinline__ unsigned agent_ld_u(const unsigned* p) {
    return __hip_atomic_load(p, __ATOMIC_RELAXED, __HIP_MEMORY_SCOPE_AGENT);
}
__device__ __forceinline__ void agent_st_u(unsigned* p, unsigned v) {
    __hip_atomic_store(p, v, __ATOMIC_RELAXED, __HIP_MEMORY_SCOPE_AGENT);
}
__device__ __forceinline__ unsigned long long agent_ld_u64(const unsigned long long* p) {
    return __hip_atomic_load(p, __ATOMIC_RELAXED, __HIP_MEMORY_SCOPE_AGENT);
}

__device__ __forceinline__ float fdot2(h2 a, h2 b, float c) {
#if __has_builtin(__builtin_amdgcn_fdot2)
    return __builtin_amdgcn_fdot2(a, b, c, false);
#else
    return c + (float)a.x * (float)b.x + (float)a.y * (float)b.y;
#endif
}
__device__ __forceinline__ float sigf(float x) { return 1.0f / (1.0f + expf(-x)); }

// grid barrier: sense-reversing, agent-scope atomics only (no cache flush ->
// read-only streams stay L2-resident across steps)
__device__ __forceinline__ void gbar(unsigned* bar) {
    __syncthreads();
    if (threadIdx.x == 0) {
        unsigned g = __hip_atomic_load(bar + 1, __ATOMIC_RELAXED, __HIP_MEMORY_SCOPE_AGENT);
        unsigned a = __hip_atomic_fetch_add(bar, 1u, __ATOMIC_ACQ_REL, __HIP_MEMORY_SCOPE_AGENT);
        if (a == gridDim.x - 1) {
            __hip_atomic_store(bar, 0u, __ATOMIC_RELAXED, __HIP_MEMORY_SCOPE_AGENT);
            __hip_atomic_store(bar + 1, g + 1, __ATOMIC_RELEASE, __HIP_MEMORY_SCOPE_AGENT);
        } else {
            while (__hip_atomic_load(bar + 1, __ATOMIC_RELAXED, __HIP_MEMORY_SCOPE_AGENT) == g)
                __builtin_amdgcn_s_sleep(1);
            (void)__hip_atomic_load(bar + 1, __ATOMIC_ACQUIRE, __HIP_MEMORY_SCOPE_AGENT);
        }
    }
    __syncthreads();
}

// ---------------- prep: weight conversion / packing ----------------
// W_encT[n][k] fp16 ; W_fcT[n][k] fp16 (padded to 10112 rows, zeros past 10000)
// Wdf8: k8-packed cols [dec_att 512 | f_beta 512]: ((k/8)*1024 + col)*8 + k%8
// Wcat8: k8-packed, col-permuted n' = j*4+g (n = g*512+j), K=1536 (=[W_ih;W_hh])
__global__ void k_prep_w(const float* W_enc, const float* W_fc,
                         const float* W_dec, const float* W_fb,
                         const float* W_ih, const float* W_hh,
                         const float* b_dec, const float* b_fb,
                         const float* b_ih, const float* b_hh,
                         f16* W_encT, f16* W_fcT, f16* Wdf8, f16* Wcat8,
                         float* b_df, float* b_cat) {
    const int S0 = 512 * 512;
    const int S1 = 10112 * 512;
    const int S2 = 512 * 1024;
    const int S3 = 1536 * 2048;
    const int total = S0 + S1 + S2 + S3 + 1024 + 2048;
    for (int idx = blockIdx.x * 256 + threadIdx.x; idx < total; idx += gridDim.x * 256) {
        int i = idx;
        if (i < S0) { int n = i >> 9, k = i & 511; W_encT[i] = (f16)W_enc[k * 512 + n]; continue; }
        i -= S0;
        if (i < S1) {
            int n = i >> 9, k = i & 511;
            W_fcT[i] = (n < 10000) ? (f16)W_fc[(long)k * 10000 + n] : (f16)0.0f;
            continue;
        }
        i -= S1;
        if (i < S2) {
            int k8 = i / 8192, r = i % 8192, col = r >> 3, kr = r & 7;
            int k = k8 * 8 + kr;
            float v = (col < 512) ? W_dec[k * 512 + col] : W_fb[k * 512 + (col - 512)];
            Wdf8[i] = (f16)v;
            continue;
        }
        i -= S2;
        if (i < S3) {
            int k8 = i / 16384, r = i % 16384, np = r >> 3, kr = r & 7;
            int k = k8 * 8 + kr;
            int j = np >> 2, g = np & 3, n = g * 512 + j;
            float v = (k < 1024) ? W_ih[(long)k * 2048 + n] : W_hh[(long)(k - 1024) * 2048 + n];
            Wcat8[i] = (f16)v;
            continue;
        }
        i -= S3;
        if (i < 1024) { b_df[i] = (i < 512) ? b_dec[i] : b_fb[i - 512]; continue; }
        i -= 1024;
        { int j = i >> 2, g = i & 3, n = g * 512 + j; b_cat[i] = b_ih[n] + b_hh[n]; }
    }
}

// ---------------- prep: enc transpose + mean ----------------
// enc_t[b][p][c] fp16 from encoder_out[b][c][p] fp32 ; mean_enc[b][c] fp32
__global__ void k_prep_enc(const float* enc_out, f16* enc_t, float* mean_enc) {
    __shared__ float tile[64][197];
    int b = blockIdx.x >> 3, cc = blockIdx.x & 7, c0 = cc * 64;
    int t = threadIdx.x;
    const float* src = enc_out + ((long)b * 512 + c0) * 196;
    for (int i = 0; i < 49; ++i) {
        int lin = t + i * 256;          // 0..12543 = 64*196
        int cl = lin / 196, p = lin % 196;
        tile[cl][p] = src[cl * 196 + p];
    }
    __syncthreads();
    if (t < 64) {
        float s = 0.f;
        for (int p = 0; p < 196; ++p) s += tile[t][p];
        mean_enc[b * 512 + c0 + t] = s * (1.0f / 196.0f);
    }
    __syncthreads();
    int cl = t & 63, pg = t >> 6;
    for (int i = 0; i < 49; ++i) {
        int p = pg * 49 + i;
        enc_t[((long)(b * 196 + p)) * 512 + c0 + cl] = (f16)tile[cl][p];
    }
}

// ---------------- h0/c0 + misc init ----------------
__global__ void k_h0c0(const float* mean_enc, const float* W_init_h, const float* b_init_h,
                       const float* W_init_c, const float* b_init_c,
                       float* c, f16* h_h, f16* h_all, unsigned* bar) {
    if (blockIdx.x == 64) {
        int t = threadIdx.x;
        if (t < 2) bar[t] = 0u;
        for (int i = t; i < 32 * 512; i += 256) h_all[(long)2016 * 512 + i] = (f16)0.0f;
        return;
    }
    __shared__ float ms[512];
    int b = blockIdx.x >> 1, which = blockIdx.x & 1;
    const float* W = which ? W_init_c : W_init_h;
    const float* bb = which ? b_init_c : b_init_h;
    int t = threadIdx.x;
    ms[t] = mean_enc[b * 512 + t];
    ms[t + 256] = mean_enc[b * 512 + t + 256];
    __syncthreads();
    for (int jj = 0; jj < 2; ++jj) {
        int j = t + jj * 256;
        float acc = bb[j];
        for (int k = 0; k < 512; ++k) acc += ms[k] * W[k * 512 + j];
        if (which) c[b * 512 + j] = acc;
        else h_h[b * 512 + j] = (f16)acc;
    }
}

// ---------------- enc_att = enc @ W_enc_att + b (fp16 MFMA) ----------------
// A rows = 6272 (b*196+p), K=512, N=512. Out fp16.
__global__ __launch_bounds__(256, 2) void k_encatt(const f16* A, const f16* Bt,
                                                   const float* bias, f16* Cout) {
    __shared__ __align__(16) f16 As[128 * 32];
    __shared__ __align__(16) f16 Bs[128 * 32];
    int m0 = blockIdx.x * 128, n0 = blockIdx.y * 128;
    int t = threadIdx.x, w = t >> 6, lane = t & 63;
    int wm = (w >> 1) * 64, wn = (w & 1) * 64;
    int lm = lane & 15, lq = lane >> 4;
    f4v acc[4][4];
    for (int mi = 0; mi < 4; ++mi)
        for (int ni = 0; ni < 4; ++ni) acc[mi][ni] = (f4v){0.f, 0.f, 0.f, 0.f};
    for (int kb = 0; kb < 512; kb += 32) {
        for (int i = 0; i < 2; ++i) {
            int li = t + i * 256;
            int row = li >> 2, q = li & 3;
            *(uint4*)&As[row * 32 + q * 8] = *(const uint4*)&A[(long)(m0 + row) * 512 + kb + q * 8];
            *(uint4*)&Bs[row * 32 + q * 8] = *(const uint4*)&Bt[(long)(n0 + row) * 512 + kb + q * 8];
        }
        __syncthreads();
        h8 af[4], bf[4];
        for (int i = 0; i < 4; ++i) {
            af[i] = *(const h8*)&As[(wm + i * 16 + lm) * 32 + lq * 8];
            bf[i] = *(const h8*)&Bs[(wn + i * 16 + lm) * 32 + lq * 8];
        }
        for (int mi = 0; mi < 4; ++mi)
            for (int ni = 0; ni < 4; ++ni)
                acc[mi][ni] = __builtin_amdgcn_mfma_f32_16x16x32_f16(af[mi], bf[ni], acc[mi][ni], 0, 0, 0);
        __syncthreads();
    }
    for (int mi = 0; mi < 4; ++mi)
        for (int ni = 0; ni < 4; ++ni)
            for (int r = 0; r < 4; ++r) {
                int row = m0 + wm + mi * 16 + lq * 4 + r;
                int col = n0 + wn + ni * 16 + lm;
                Cout[(long)row * 512 + col] = (f16)(acc[mi][ni][r] + bias[col]);
            }
}

// ---------------- final FC: preds = h_all @ W_fc + b_fc (fp16 MFMA, masked) ----------------
__global__ __launch_bounds__(256, 2) void k_fc(const f16* A, const f16* Bt, const float* bias,
                                               const int* cl, float* out) {
    __shared__ __align__(16) f16 As[128 * 32];
    __shared__ __align__(16) f16 Bs[128 * 32];
    int m0 = blockIdx.x * 128, n0 = blockIdx.y * 128;
    int t = threadIdx.x, w = t >> 6, lane = t & 63;
    int wm = (w >> 1) * 64, wn = (w & 1) * 64;
    int lm = lane & 15, lq = lane >> 4;

    // skip fully-inactive row blocks (still must write zeros: out is poisoned)
    bool myact = false;
    if (t < 128) {
        int row = m0 + t;
        if (row < 2016) {
            int b = row / 63, tt = row - b * 63;
            myact = tt < (cl[b] - 1);
        }
    }
    int anyact = __syncthreads_or((int)myact);
    if (!anyact) {
        for (int i = 0; i < 64; ++i) {
            int idx = t + i * 256;
            int row = m0 + (idx >> 7), col = n0 + (idx & 127);
            if (row < 2016 && col < 10000) out[(long)row * 10000 + col] = 0.0f;
        }
        return;
    }

    f4v acc[4][4];
    for (int mi = 0; mi < 4; ++mi)
        for (int ni = 0; ni < 4; ++ni) acc[mi][ni] = (f4v){0.f, 0.f, 0.f, 0.f};
    for (int kb = 0; kb < 512; kb += 32) {
        for (int i = 0; i < 2; ++i) {
            int li = t + i * 256;
            int row = li >> 2, q = li & 3;
            *(uint4*)&As[row * 32 + q * 8] = *(const uint4*)&A[(long)(m0 + row) * 512 + kb + q * 8];
            *(uint4*)&Bs[row * 32 + q * 8] = *(const uint4*)&Bt[(long)(n0 + row) * 512 + kb + q * 8];
        }
        __syncthreads();
        h8 af[4], bf[4];
        for (int i = 0; i < 4; ++i) {
            af[i] = *(const h8*)&As[(wm + i * 16 + lm) * 32 + lq * 8];
            bf[i] = *(const h8*)&Bs[(wn + i * 16 + lm) * 32 + lq * 8];
        }
        for (int mi = 0; mi < 4; ++mi)
            for (int ni = 0; ni < 4; ++ni)
                acc[mi][ni] = __builtin_amdgcn_mfma_f32_16x16x32_f16(af[mi], bf[ni], acc[mi][ni], 0, 0, 0);
        __syncthreads();
    }
    for (int mi = 0; mi < 4; ++mi)
        for (int ni = 0; ni < 4; ++ni)
            for (int r = 0; r < 4; ++r) {
                int row = m0 + wm + mi * 16 + lq * 4 + r;
                int col = n0 + wn + ni * 16 + lm;
                if (row < 2016 && col < 10000) {
                    int b = row / 63, tt = row - b * 63;
                    bool act = tt < (cl[b] - 1);
                    out[(long)row * 10000 + col] = act ? (acc[mi][ni][r] + bias[col]) : 0.0f;
                }
            }
}

// ---------------- persistent recurrent loop ----------------
// 256 blocks x 256 threads, 63 steps, 4 grid barriers/step.
// Phase A: dec_a / gate_pre = h @ [W_dec_att | W_f_beta] + b      (128 blocks)
// Phase B: score[b][p] = relu(enc_att + dec_a) . W_full           (1024 waves)
// Phase D: softmax(p) + awe + build xh = [e_t | gate*awe | h]     (256 blocks)
// Phase E: gates = xh @ Wcat + b ; LSTM pointwise ; h/c update    (256 blocks)
__global__ __launch_bounds__(256, 2) void k_loop(
    const f16* Wdf8, const float* b_df,
    const f16* Wcat8, const float* b_cat,
    const f16* enc_att_h, const f16* enc_t,
    const float* W_full, const float* emb, const int* caps, const int* cl,
    float* c, f16* h_h, float* da_gp, float* score, f16* xh, f16* h_all,
    unsigned* bar) {
    __shared__ float sm[768];
    const int bid = blockIdx.x, t = threadIdx.x;
    const int lane = t & 63, w = t >> 6;

    for (int step = 0; step < 63; ++step) {
        // ---- Phase A ----
        if (bid < 128) {
            int cc = bid & 15, bq = bid >> 4;
            int col = cc * 64 + lane;
            int b = bq * 4 + w;
            const f16* wp = Wdf8 + (long)col * 8;
            const unsigned* hp = (const unsigned*)(h_h + (long)b * 512);
            float acc0 = 0.f, acc1 = 0.f;
            for (int k8 = 0; k8 < 64; k8 += 2) {
                uint4 wa = *(const uint4*)(wp + (long)k8 * 8192);
                uint4 wb = *(const uint4*)(wp + ((long)k8 + 1) * 8192);
                unsigned x0 = agent_ld_u(hp + k8 * 4 + 0);
                unsigned x1 = agent_ld_u(hp + k8 * 4 + 1);
                unsigned x2 = agent_ld_u(hp + k8 * 4 + 2);
                unsigned x3 = agent_ld_u(hp + k8 * 4 + 3);
                unsigned x4 = agent_ld_u(hp + k8 * 4 + 4);
                unsigned x5 = agent_ld_u(hp + k8 * 4 + 5);
                unsigned x6 = agent_ld_u(hp + k8 * 4 + 6);
                unsigned x7 = agent_ld_u(hp + k8 * 4 + 7);
                acc0 = fdot2(u2h2(x0), u2h2(wa.x), acc0);
                acc0 = fdot2(u2h2(x1), u2h2(wa.y), acc0);
                acc0 = fdot2(u2h2(x2), u2h2(wa.z), acc0);
                acc0 = fdot2(u2h2(x3), u2h2(wa.w), acc0);
                acc1 = fdot2(u2h2(x4), u2h2(wb.x), acc1);
                acc1 = fdot2(u2h2(x5), u2h2(wb.y), acc1);
                acc1 = fdot2(u2h2(x6), u2h2(wb.z), acc1);
                acc1 = fdot2(u2h2(x7), u2h2(wb.w), acc1);
            }
            agent_st_f(da_gp + (long)b * 1024 + col, acc0 + acc1 + b_df[col]);
        }
        gbar(bar);

        // ---- Phase B ----
        {
            int gw = bid * 4 + w;
            for (int r = 0; r < 7; ++r) {
                int idx = gw + r * 1024;
                if (idx < 6272) {
                    int b = idx / 196;
                    uint4 ev = *(const uint4*)(enc_att_h + (long)idx * 512 + lane * 8);
                    const unsigned long long* dp =
                        (const unsigned long long*)(da_gp + (long)b * 1024 + lane * 8);
                    float2 d0 = u2f2(agent_ld_u64(dp + 0));
                    float2 d1 = u2f2(agent_ld_u64(dp + 1));
                    float2 d2 = u2f2(agent_ld_u64(dp + 2));
                    float2 d3 = u2f2(agent_ld_u64(dp + 3));
                    float4 wa4 = *(const float4*)(W_full + lane * 8);
                    float4 wb4 = *(const float4*)(W_full + lane * 8 + 4);
                    h2 e0 = u2h2(ev.x), e1 = u2h2(ev.y), e2 = u2h2(ev.z), e3 = u2h2(ev.w);
                    float a = 0.f;
                    a += fmaxf((float)e0.x + d0.x, 0.f) * wa4.x;
                    a += fmaxf((float)e0.y + d0.y, 0.f) * wa4.y;
                    a += fmaxf((float)e1.x + d1.x, 0.f) * wa4.z;
                    a += fmaxf((float)e1.y + d1.y, 0.f) * wa4.w;
                    a += fmaxf((float)e2.x + d2.x, 0.f) * wb4.x;
                    a += fmaxf((float)e2.y + d2.y, 0.f) * wb4.y;
                    a += fmaxf((float)e3.x + d3.x, 0.f) * wb4.z;
                    a += fmaxf((float)e3.y + d3.y, 0.f) * wb4.w;
                    for (int m = 32; m; m >>= 1) a += __shfl_xor(a, m);
                    if (lane == 0) agent_st_f(score + idx, a);
                }
            }
        }
        gbar(bar);

        // ---- Phase D ----
        {
            int b = bid >> 3, cc = bid & 7, c0 = cc * 64;
            float* score_s = sm;
            float* alpha_s = sm + 200;
            float* part_s = sm + 400;
            if (t < 196) score_s[t] = agent_ld_f(score + b * 196 + t);
            __syncthreads();
            if (w == 0) {
                float v[4], e[4];
                float m = -1e30f;
                for (int i = 0; i < 4; ++i) {
                    int p = lane + i * 64;
                    v[i] = (p < 196) ? score_s[p] : -1e30f;
                    m = fmaxf(m, v[i]);
                }
                for (int mm = 32; mm; mm >>= 1) m = fmaxf(m, __shfl_xor(m, mm));
                float s = 0.f;
                for (int i = 0; i < 4; ++i) {
                    int p = lane + i * 64;
                    e[i] = (p < 196) ? expf(v[i] - m) : 0.f;
                    s += e[i];
                }
                for (int mm = 32; mm; mm >>= 1) s += __shfl_xor(s, mm);
                float inv = 1.0f / s;
                for (int i = 0; i < 4; ++i) {
                    int p = lane + i * 64;
                    if (p < 196) alpha_s[p] = e[i] * inv;
                }
            }
            __syncthreads();
            {
                int cx = t & 63, pg = t >> 6;
                float partial = 0.f;
                const f16* ep = enc_t + ((long)b * 196) * 512 + c0 + cx;
                for (int i = 0; i < 49; ++i) {
                    int p = pg * 49 + i;
                    partial += alpha_s[p] * (float)ep[(long)p * 512];
                }
                part_s[pg * 64 + cx] = partial;
            }
            __syncthreads();
            if (t < 32) {
                int ca = c0 + 2 * t;
                float awe0 = part_s[2 * t] + part_s[64 + 2 * t] + part_s[128 + 2 * t] + part_s[192 + 2 * t];
                float awe1 = part_s[2 * t + 1] + part_s[64 + 2 * t + 1] + part_s[128 + 2 * t + 1] + part_s[192 + 2 * t + 1];
                float gp0 = agent_ld_f(da_gp + (long)b * 1024 + 512 + ca);
                float gp1 = agent_ld_f(da_gp + (long)b * 1024 + 512 + ca + 1);
                float g0 = sigf(gp0), g1 = sigf(gp1);
                int tok = caps[b * 64 + step];
                float e0 = emb[(long)tok * 512 + ca];
                float e1 = emb[(long)tok * 512 + ca + 1];
                unsigned* xp = (unsigned*)(xh + (long)b * 1536);
                int ci = (c0 >> 1) + t;
                h2 pe; pe.x = (f16)e0; pe.y = (f16)e1;
                agent_st_u(xp + ci, h22u(pe));
                h2 pa; pa.x = (f16)(g0 * awe0); pa.y = (f16)(g1 * awe1);
                agent_st_u(xp + 256 + ci, h22u(pa));
                unsigned hv = agent_ld_u((const unsigned*)(h_h + (long)b * 512) + ci);
                agent_st_u(xp + 512 + ci, hv);
            }
        }
        gbar(bar);

        // ---- Phase E ----
        {
            int bh = bid & 1, nc = bid >> 1;    // nc 0..127 -> j0 = nc*4
            int nl = t & 15, bl = t >> 4;
            int b = bh * 16 + bl;
            int np = nc * 16 + nl;
            const f16* wp = Wcat8 + (long)np * 8;
            const unsigned* xp = (const unsigned*)(xh + (long)b * 1536);
            float acc0 = 0.f, acc1 = 0.f;
            for (int k8 = 0; k8 < 192; k8 += 2) {
                uint4 wa = *(const uint4*)(wp + (long)k8 * 16384);
                uint4 wb = *(const uint4*)(wp + ((long)k8 + 1) * 16384);
                unsigned x0 = agent_ld_u(xp + k8 * 4 + 0);
                unsigned x1 = agent_ld_u(xp + k8 * 4 + 1);
                unsigned x2 = agent_ld_u(xp + k8 * 4 + 2);
                unsigned x3 = agent_ld_u(xp + k8 * 4 + 3);
                unsigned x4 = agent_ld_u(xp + k8 * 4 + 4);
                unsigned x5 = agent_ld_u(xp + k8 * 4 + 5);
                unsigned x6 = agent_ld_u(xp + k8 * 4 + 6);
                unsigned x7 = agent_ld_u(xp + k8 * 4 + 7);
                acc0 = fdot2(u2h2(x0), u2h2(wa.x), acc0);
                acc0 = fdot2(u2h2(x1), u2h2(wa.y), acc0);
                acc0 = fdot2(u2h2(x2), u2h2(wa.z), acc0);
                acc0 = fdot2(u2h2(x3), u2h2(wa.w), acc0);
                acc1 = fdot2(u2h2(x4), u2h2(wb.x), acc1);
                acc1 = fdot2(u2h2(x5), u2h2(wb.y), acc1);
                acc1 = fdot2(u2h2(x6), u2h2(wb.z), acc1);
                acc1 = fdot2(u2h2(x7), u2h2(wb.w), acc1);
            }
            sm[bl * 16 + nl] = acc0 + acc1 + b_cat[np];
            __syncthreads();
            if (t < 32) {
                int bl2 = t >> 1, jp = t & 1;
                int b2 = bh * 16 + bl2;
                int j0 = nc * 4, jbase = j0 + jp * 2;
                unsigned* hhp = (unsigned*)(h_h + (long)b2 * 512) + (jbase >> 1);
                h2 oldh = u2h2(agent_ld_u(hhp));
                bool act = step < (cl[b2] - 1);
                h2 outp;
                for (int q = 0; q < 2; ++q) {
                    int jj = jp * 2 + q, j = j0 + jj;
                    float gi = sm[bl2 * 16 + jj * 4 + 0];
                    float gf = sm[bl2 * 16 + jj * 4 + 1];
                    float gg = sm[bl2 * 16 + jj * 4 + 2];
                    float go = sm[bl2 * 16 + jj * 4 + 3];
                    float cold = c[(long)b2 * 512 + j];
                    float cn = sigf(gf) * cold + sigf(gi) * tanhf(gg);
                    float hn = sigf(go) * tanhf(cn);
                    float hv, cv;
                    if (act) { hv = hn; cv = cn; }
                    else { hv = (float)(q ? oldh.y : oldh.x); cv = cold; }
                    c[(long)b2 * 512 + j] = cv;
                    if (q) outp.y = (f16)hv; else outp.x = (f16)hv;
                }
                unsigned pv = h22u(outp);
                agent_st_u(hhp, pv);
                *(unsigned*)(h_all + ((long)b2 * 63 + step) * 512 + jbase) = pv;
            }
            __syncthreads();
        }
        gbar(bar);
    }
}

// ---------------- launcher ----------------
extern "C" void kernel_launch(void* const* d_in, const int* in_sizes, int n_in,
                              void* d_out, int out_size, void* d_ws, size_t ws_size,
                              hipStream_t stream) {
    const float* encoder_out = (const float*)d_in[0];
    const int* caps = (const int*)d_in[1];
    const int* cl = (const int*)d_in[2];
    const float* emb = (const float*)d_in[3];
    const float* W_enc_att = (const float*)d_in[4];
    const float* b_enc_att = (const float*)d_in[5];
    const float* W_dec_att = (const float*)d_in[6];
    const float* b_dec_att = (const float*)d_in[7];
    const float* W_full_att = (const float*)d_in[8];
    const float* W_init_h = (const float*)d_in[10];
    const float* b_init_h = (const float*)d_in[11];
    const float* W_init_c = (const float*)d_in[12];
    const float* b_init_c = (const float*)d_in[13];
    const float* W_f_beta = (const float*)d_in[14];
    const float* b_f_beta = (const float*)d_in[15];
    const float* W_ih = (const float*)d_in[16];
    const float* b_ih = (const float*)d_in[17];
    const float* W_hh = (const float*)d_in[18];
    const float* b_hh = (const float*)d_in[19];
    const float* W_fc = (const float*)d_in[20];
    const float* b_fc = (const float*)d_in[21];

    char* p = (char*)d_ws;
    auto take = [&](size_t bytes) {
        char* r = p;
        p += (bytes + 255) & ~(size_t)255;
        return r;
    };
    f16* enc_t     = (f16*)take((size_t)32 * 196 * 512 * 2);
    f16* enc_att_h = (f16*)take((size_t)32 * 196 * 512 * 2);
    f16* W_encT    = (f16*)take((size_t)512 * 512 * 2);
    f16* W_fcT     = (f16*)take((size_t)10112 * 512 * 2);
    f16* Wdf8      = (f16*)take((size_t)512 * 1024 * 2);
    f16* Wcat8     = (f16*)take((size_t)1536 * 2048 * 2);
    f16* h_all     = (f16*)take((size_t)2048 * 512 * 2);
    f16* h_h       = (f16*)take((size_t)32 * 512 * 2);
    f16* xh        = (f16*)take((size_t)32 * 1536 * 2);
    float* b_df    = (float*)take(1024 * 4);
    float* b_cat   = (float*)take(2048 * 4);
    float* mean_e  = (float*)take((size_t)32 * 512 * 4);
    float* c_st    = (float*)take((size_t)32 * 512 * 4);
    float* da_gp   = (float*)take((size_t)32 * 1024 * 4);
    float* score   = (float*)take((size_t)32 * 196 * 4);
    unsigned* bar  = (unsigned*)take(256);

    k_prep_w<<<2048, 256, 0, stream>>>(W_enc_att, W_fc, W_dec_att, W_f_beta, W_ih, W_hh,
                                       b_dec_att, b_f_beta, b_ih, b_hh,
                                       W_encT, W_fcT, Wdf8, Wcat8, b_df, b_cat);
    k_prep_enc<<<256, 256, 0, stream>>>(encoder_out, enc_t, mean_e);
    k_h0c0<<<65, 256, 0, stream>>>(mean_e, W_init_h, b_init_h, W_init_c, b_init_c,
                                   c_st, h_h, h_all, bar);
    k_encatt<<<dim3(49, 4), 256, 0, stream>>>(enc_t, W_encT, b_enc_att, enc_att_h);
    k_loop<<<256, 256, 0, stream>>>(Wdf8, b_df, Wcat8, b_cat, enc_att_h, enc_t,
                                    W_full_att, emb, caps, cl,
                                    c_st, h_h, da_gp, score, xh, h_all, bar);
    k_fc<<<dim3(16, 79), 256, 0, stream>>>(h_all, W_fcT, b_fc, cl, (float*)d_out);
}

// Round 2
// 5320.095 us; speedup vs baseline: 1.6216x; 1.6216x over previous
//
#include <hip/hip_runtime.h>
#include <cstdint>
#include <cstddef>

// ---------------- problem constants ----------------
// B=32, ENC=512, P=196 (14x14), ATT=512, EMB=512, DEC=512, VOCAB=10000, T=63
typedef _Float16 f16;
typedef _Float16 h2 __attribute__((ext_vector_type(2)));
typedef _Float16 h8 __attribute__((ext_vector_type(8)));
typedef float f4v __attribute__((ext_vector_type(4)));

// ---------------- helpers ----------------
__device__ __forceinline__ h2 u2h2(unsigned u) { return __builtin_bit_cast(h2, u); }
__device__ __forceinline__ unsigned h22u(h2 v) { return __builtin_bit_cast(unsigned, v); }
__device__ __forceinline__ float2 u2f2(unsigned long long u) { return __builtin_bit_cast(float2, u); }

__device__ __forceinline__ float agent_ld_f(const float* p) {
    return __hip_atomic_load(p, __ATOMIC_RELAXED, __HIP_MEMORY_SCOPE_AGENT);
}
__device__ __forceinline__ void agent_st_f(float* p, float v) {
    __hip_atomic_store(p, v, __ATOMIC_RELAXED, __HIP_MEMORY_SCOPE_AGENT);
}
__device__ __forceinline__ unsigned agent_ld_u(const unsigned* p) {
    return __hip_atomic_load(p, __ATOMIC_RELAXED, __HIP_MEMORY_SCOPE_AGENT);
}
__device__ __forceinline__ void agent_st_u(unsigned* p, unsigned v) {
    __hip_atomic_store(p, v, __ATOMIC_RELAXED, __HIP_MEMORY_SCOPE_AGENT);
}
__device__ __forceinline__ unsigned long long agent_ld_u64(const unsigned long long* p) {
    return __hip_atomic_load(p, __ATOMIC_RELAXED, __HIP_MEMORY_SCOPE_AGENT);
}

__device__ __forceinline__ float fdot2(h2 a, h2 b, float c) {
#if __has_builtin(__builtin_amdgcn_fdot2)
    return __builtin_amdgcn_fdot2(a, b, c, false);
#else
    return c + (float)a.x * (float)b.x + (float)a.y * (float)b.y;
#endif
}
__device__ __forceinline__ float sigf(float x) { return 1.0f / (1.0f + expf(-x)); }

// grid barrier: store-based arrival (no RMW contention), master poll + broadcast
// release flag. agent-scope only -> no L2 writeback; read-only streams stay hot.
// arrive = bar[0..255], release = bar[384] (separate cacheline).
__device__ __forceinline__ void gbar(unsigned* arrive, unsigned* release, unsigned epoch) {
    __syncthreads();
    if (blockIdx.x == 0) {
        if (threadIdx.x < 64) {
            int l = threadIdx.x;
            if (l == 0)
                __hip_atomic_store(&arrive[0], epoch, __ATOMIC_RELEASE, __HIP_MEMORY_SCOPE_AGENT);
            bool ok;
            do {
                ok = true;
#pragma unroll
                for (int i = 0; i < 4; ++i)
                    ok = ok && (__hip_atomic_load(&arrive[l + i * 64], __ATOMIC_RELAXED,
                                                  __HIP_MEMORY_SCOPE_AGENT) == epoch);
                if (!ok) __builtin_amdgcn_s_sleep(1);
            } while (__ballot(ok) != ~0ull);
            __builtin_amdgcn_fence(__ATOMIC_ACQUIRE, "agent");
            if (l == 0)
                __hip_atomic_store(release, epoch, __ATOMIC_RELEASE, __HIP_MEMORY_SCOPE_AGENT);
        }
    } else {
        if (threadIdx.x == 0) {
            __hip_atomic_store(&arrive[blockIdx.x], epoch, __ATOMIC_RELEASE, __HIP_MEMORY_SCOPE_AGENT);
            while (__hip_atomic_load(release, __ATOMIC_RELAXED, __HIP_MEMORY_SCOPE_AGENT) != epoch)
                __builtin_amdgcn_s_sleep(1);
            __builtin_amdgcn_fence(__ATOMIC_ACQUIRE, "agent");
        }
    }
    __syncthreads();
}

// ---------------- prep: small weights / biases ----------------
// W_encT[n][k] fp16 ; Wdf8 k8-packed cols [dec_att 512 | f_beta 512]
// b_df = [b_dec | b_fb] ; b_cat[n] = b_ih[n] + b_hh[n] (natural order)
__global__ void k_prep_w(const float* W_enc, const float* W_dec, const float* W_fb,
                         const float* b_dec, const float* b_fb,
                         const float* b_ih, const float* b_hh,
                         f16* W_encT, f16* Wdf8, float* b_df, float* b_cat) {
    const int S0 = 512 * 512;
    const int S2 = 512 * 1024;
    const int total = S0 + S2 + 1024 + 2048;
    for (int idx = blockIdx.x * 256 + threadIdx.x; idx < total; idx += gridDim.x * 256) {
        int i = idx;
        if (i < S0) { int n = i >> 9, k = i & 511; W_encT[i] = (f16)W_enc[k * 512 + n]; continue; }
        i -= S0;
        if (i < S2) {
            int k8 = i / 8192, r = i % 8192, col = r >> 3, kr = r & 7;
            int k = k8 * 8 + kr;
            float v = (col < 512) ? W_dec[k * 512 + col] : W_fb[k * 512 + (col - 512)];
            Wdf8[i] = (f16)v;
            continue;
        }
        i -= S2;
        if (i < 1024) { b_df[i] = (i < 512) ? b_dec[i] : b_fb[i - 512]; continue; }
        i -= 1024;
        b_cat[i] = b_ih[i] + b_hh[i];
    }
}

// ---------------- prep: tiled transpose W_fc -> W_fcT[n][k] fp16 ----------------
__global__ void k_tr_fc(const float* W_fc, f16* W_fcT) {
    __shared__ float tile[64][65];
    int n0 = blockIdx.x * 64;   // 158 tiles -> 10112 (zero-pad past 10000)
    int k0 = blockIdx.y * 64;   // 8 tiles
    int t = threadIdx.x;
#pragma unroll
    for (int i = 0; i < 16; ++i) {
        int lin = t + i * 256;
        int kl = lin >> 6, nl = lin & 63;
        int n = n0 + nl;
        tile[kl][nl] = (n < 10000) ? W_fc[(long)(k0 + kl) * 10000 + n] : 0.0f;
    }
    __syncthreads();
#pragma unroll
    for (int i = 0; i < 2; ++i) {
        int lin = t + i * 256;          // 512 = 64 rows x 8 vec-cols
        int r = lin >> 3, cv = lin & 7;
        f16 v[8];
#pragma unroll
        for (int kr = 0; kr < 8; ++kr) v[kr] = (f16)tile[cv * 8 + kr][r];
        *(uint4*)&W_fcT[(long)(n0 + r) * 512 + k0 + cv * 8] = *(uint4*)v;
    }
}

// ---------------- prep: tiled k8-repack [W_ih;W_hh] -> Wcat8[k8][n][kr] ----------------
__global__ void k_pack_cat(const float* W_ih, const float* W_hh, f16* Wcat8) {
    __shared__ float tile[64][65];
    int k0 = blockIdx.x * 64;   // 24 tiles (K=1536)
    int n0 = blockIdx.y * 64;   // 32 tiles (N=2048)
    int t = threadIdx.x;
#pragma unroll
    for (int i = 0; i < 16; ++i) {
        int lin = t + i * 256;
        int kl = lin >> 6, nl = lin & 63;
        int k = k0 + kl;
        float v = (k < 1024) ? W_ih[(long)k * 2048 + n0 + nl]
                             : W_hh[(long)(k - 1024) * 2048 + n0 + nl];
        tile[kl][nl] = v;
    }
    __syncthreads();
#pragma unroll
    for (int i = 0; i < 2; ++i) {
        int lin = t + i * 256;          // 512 = 8 k8 x 64 n
        int nl = lin & 63, k8l = lin >> 6;
        f16 v[8];
#pragma unroll
        for (int kr = 0; kr < 8; ++kr) v[kr] = (f16)tile[k8l * 8 + kr][nl];
        *(uint4*)&Wcat8[(long)(k0 / 8 + k8l) * 16384 + (long)(n0 + nl) * 8] = *(uint4*)v;
    }
}

// ---------------- prep: enc transpose + mean ----------------
__global__ void k_prep_enc(const float* enc_out, f16* enc_t, float* mean_enc) {
    __shared__ float tile[64][197];
    int b = blockIdx.x >> 3, cc = blockIdx.x & 7, c0 = cc * 64;
    int t = threadIdx.x;
    const float* src = enc_out + ((long)b * 512 + c0) * 196;
    for (int i = 0; i < 49; ++i) {
        int lin = t + i * 256;          // 0..12543 = 64*196
        int cl = lin / 196, p = lin % 196;
        tile[cl][p] = src[cl * 196 + p];
    }
    __syncthreads();
    if (t < 64) {
        float s = 0.f;
        for (int p = 0; p < 196; ++p) s += tile[t][p];
        mean_enc[b * 512 + c0 + t] = s * (1.0f / 196.0f);
    }
    __syncthreads();
    int cl = t & 63, pg = t >> 6;
    for (int i = 0; i < 49; ++i) {
        int p = pg * 49 + i;
        enc_t[((long)(b * 196 + p)) * 512 + c0 + cl] = (f16)tile[cl][p];
    }
}

// ---------------- h0/c0 + barrier/tail init ----------------
__global__ void k_h0c0(const float* mean_enc, const float* W_init_h, const float* b_init_h,
                       const float* W_init_c, const float* b_init_c,
                       float* c, f16* h_h, f16* h_all, unsigned* bar) {
    if (blockIdx.x == 64) {
        int t = threadIdx.x;
        for (int i = t; i < 512; i += 256) bar[i] = 0u;
        for (int i = t; i < 32 * 512; i += 256) h_all[(long)2016 * 512 + i] = (f16)0.0f;
        return;
    }
    __shared__ float ms[512];
    int b = blockIdx.x >> 1, which = blockIdx.x & 1;
    const float* W = which ? W_init_c : W_init_h;
    const float* bb = which ? b_init_c : b_init_h;
    int t = threadIdx.x;
    ms[t] = mean_enc[b * 512 + t];
    ms[t + 256] = mean_enc[b * 512 + t + 256];
    __syncthreads();
    for (int jj = 0; jj < 2; ++jj) {
        int j = t + jj * 256;
        float acc = bb[j];
        for (int k = 0; k < 512; ++k) acc += ms[k] * W[k * 512 + j];
        if (which) c[b * 512 + j] = acc;
        else h_h[b * 512 + j] = (f16)acc;
    }
}

// ---------------- enc_att = enc @ W_enc_att + b (fp16 MFMA) ----------------
__global__ __launch_bounds__(256, 2) void k_encatt(const f16* A, const f16* Bt,
                                                   const float* bias, f16* Cout) {
    __shared__ __align__(16) f16 As[128 * 32];
    __shared__ __align__(16) f16 Bs[128 * 32];
    int m0 = blockIdx.x * 128, n0 = blockIdx.y * 128;
    int t = threadIdx.x, w = t >> 6, lane = t & 63;
    int wm = (w >> 1) * 64, wn = (w & 1) * 64;
    int lm = lane & 15, lq = lane >> 4;
    f4v acc[4][4];
    for (int mi = 0; mi < 4; ++mi)
        for (int ni = 0; ni < 4; ++ni) acc[mi][ni] = (f4v){0.f, 0.f, 0.f, 0.f};
    for (int kb = 0; kb < 512; kb += 32) {
        for (int i = 0; i < 2; ++i) {
            int li = t + i * 256;
            int row = li >> 2, q = li & 3;
            *(uint4*)&As[row * 32 + q * 8] = *(const uint4*)&A[(long)(m0 + row) * 512 + kb + q * 8];
            *(uint4*)&Bs[row * 32 + q * 8] = *(const uint4*)&Bt[(long)(n0 + row) * 512 + kb + q * 8];
        }
        __syncthreads();
        h8 af[4], bf[4];
        for (int i = 0; i < 4; ++i) {
            af[i] = *(const h8*)&As[(wm + i * 16 + lm) * 32 + lq * 8];
            bf[i] = *(const h8*)&Bs[(wn + i * 16 + lm) * 32 + lq * 8];
        }
        for (int mi = 0; mi < 4; ++mi)
            for (int ni = 0; ni < 4; ++ni)
                acc[mi][ni] = __builtin_amdgcn_mfma_f32_16x16x32_f16(af[mi], bf[ni], acc[mi][ni], 0, 0, 0);
        __syncthreads();
    }
    for (int mi = 0; mi < 4; ++mi)
        for (int ni = 0; ni < 4; ++ni)
            for (int r = 0; r < 4; ++r) {
                int row = m0 + wm + mi * 16 + lq * 4 + r;
                int col = n0 + wn + ni * 16 + lm;
                Cout[(long)row * 512 + col] = (f16)(acc[mi][ni][r] + bias[col]);
            }
}

// ---------------- final FC: preds = h_all @ W_fc + b_fc (fp16 MFMA, masked) ----------------
__global__ __launch_bounds__(256, 2) void k_fc(const f16* A, const f16* Bt, const float* bias,
                                               const int* cl, float* out) {
    __shared__ __align__(16) f16 As[128 * 32];
    __shared__ __align__(16) f16 Bs[128 * 32];
    int m0 = blockIdx.x * 128, n0 = blockIdx.y * 128;
    int t = threadIdx.x, w = t >> 6, lane = t & 63;
    int wm = (w >> 1) * 64, wn = (w & 1) * 64;
    int lm = lane & 15, lq = lane >> 4;

    bool myact = false;
    if (t < 128) {
        int row = m0 + t;
        if (row < 2016) {
            int b = row / 63, tt = row - b * 63;
            myact = tt < (cl[b] - 1);
        }
    }
    int anyact = __syncthreads_or((int)myact);
    if (!anyact) {
        for (int i = 0; i < 64; ++i) {
            int idx = t + i * 256;
            int row = m0 + (idx >> 7), col = n0 + (idx & 127);
            if (row < 2016 && col < 10000) out[(long)row * 10000 + col] = 0.0f;
        }
        return;
    }

    f4v acc[4][4];
    for (int mi = 0; mi < 4; ++mi)
        for (int ni = 0; ni < 4; ++ni) acc[mi][ni] = (f4v){0.f, 0.f, 0.f, 0.f};
    for (int kb = 0; kb < 512; kb += 32) {
        for (int i = 0; i < 2; ++i) {
            int li = t + i * 256;
            int row = li >> 2, q = li & 3;
            *(uint4*)&As[row * 32 + q * 8] = *(const uint4*)&A[(long)(m0 + row) * 512 + kb + q * 8];
            *(uint4*)&Bs[row * 32 + q * 8] = *(const uint4*)&Bt[(long)(n0 + row) * 512 + kb + q * 8];
        }
        __syncthreads();
        h8 af[4], bf[4];
        for (int i = 0; i < 4; ++i) {
            af[i] = *(const h8*)&As[(wm + i * 16 + lm) * 32 + lq * 8];
            bf[i] = *(const h8*)&Bs[(wn + i * 16 + lm) * 32 + lq * 8];
        }
        for (int mi = 0; mi < 4; ++mi)
            for (int ni = 0; ni < 4; ++ni)
                acc[mi][ni] = __builtin_amdgcn_mfma_f32_16x16x32_f16(af[mi], bf[ni], acc[mi][ni], 0, 0, 0);
        __syncthreads();
    }
    for (int mi = 0; mi < 4; ++mi)
        for (int ni = 0; ni < 4; ++ni)
            for (int r = 0; r < 4; ++r) {
                int row = m0 + wm + mi * 16 + lq * 4 + r;
                int col = n0 + wn + ni * 16 + lm;
                if (row < 2016 && col < 10000) {
                    int b = row / 63, tt = row - b * 63;
                    bool act = tt < (cl[b] - 1);
                    out[(long)row * 10000 + col] = act ? (acc[mi][ni][r] + bias[col]) : 0.0f;
                }
            }
}

// ---------------- persistent recurrent loop ----------------
// 256 blocks x 256 threads, 63 steps, 4 grid barriers/step.
__global__ __launch_bounds__(256, 2) void k_loop(
    const f16* Wdf8, const float* b_df,
    const f16* Wcat8, const float* b_cat,
    const f16* enc_att_h, const f16* enc_t,
    const float* W_full, const float* emb, const int* caps, const int* cl,
    float* c, f16* h_h, float* da_gp, float* score, f16* xh, f16* h_all,
    unsigned* bar) {
    __shared__ float sm[768];
    const int bid = blockIdx.x, t = threadIdx.x;
    const int lane = t & 63, w = t >> 6;
    unsigned* arrive = bar;
    unsigned* release = bar + 384;

    for (int step = 0; step < 63; ++step) {
        unsigned ep = (unsigned)step * 4u;
        // ---- Phase A: dec_a / gate_pre = h @ [W_dec_att | W_f_beta] + b ----
        if (bid < 128) {
            int cc = bid & 15, bq = bid >> 4;
            int col = cc * 64 + lane;
            int b = bq * 4 + w;
            const f16* wp = Wdf8 + (long)col * 8;
            const unsigned* hp = (const unsigned*)(h_h + (long)b * 512);
            float acc0 = 0.f, acc1 = 0.f;
            for (int k8 = 0; k8 < 64; k8 += 2) {
                uint4 wa = *(const uint4*)(wp + (long)k8 * 8192);
                uint4 wb = *(const uint4*)(wp + ((long)k8 + 1) * 8192);
                unsigned x0 = agent_ld_u(hp + k8 * 4 + 0);
                unsigned x1 = agent_ld_u(hp + k8 * 4 + 1);
                unsigned x2 = agent_ld_u(hp + k8 * 4 + 2);
                unsigned x3 = agent_ld_u(hp + k8 * 4 + 3);
                unsigned x4 = agent_ld_u(hp + k8 * 4 + 4);
                unsigned x5 = agent_ld_u(hp + k8 * 4 + 5);
                unsigned x6 = agent_ld_u(hp + k8 * 4 + 6);
                unsigned x7 = agent_ld_u(hp + k8 * 4 + 7);
                acc0 = fdot2(u2h2(x0), u2h2(wa.x), acc0);
                acc0 = fdot2(u2h2(x1), u2h2(wa.y), acc0);
                acc0 = fdot2(u2h2(x2), u2h2(wa.z), acc0);
                acc0 = fdot2(u2h2(x3), u2h2(wa.w), acc0);
                acc1 = fdot2(u2h2(x4), u2h2(wb.x), acc1);
                acc1 = fdot2(u2h2(x5), u2h2(wb.y), acc1);
                acc1 = fdot2(u2h2(x6), u2h2(wb.z), acc1);
                acc1 = fdot2(u2h2(x7), u2h2(wb.w), acc1);
            }
            agent_st_f(da_gp + (long)b * 1024 + col, acc0 + acc1 + b_df[col]);
        }
        gbar(arrive, release, ep + 1u);

        // ---- Phase B: score = relu(enc_att + dec_a) . W_full ----
        {
            int gw = bid * 4 + w;
            for (int r = 0; r < 7; ++r) {
                int idx = gw + r * 1024;
                if (idx < 6272) {
                    int b = idx / 196;
                    uint4 ev = *(const uint4*)(enc_att_h + (long)idx * 512 + lane * 8);
                    const unsigned long long* dp =
                        (const unsigned long long*)(da_gp + (long)b * 1024 + lane * 8);
                    float2 d0 = u2f2(agent_ld_u64(dp + 0));
                    float2 d1 = u2f2(agent_ld_u64(dp + 1));
                    float2 d2 = u2f2(agent_ld_u64(dp + 2));
                    float2 d3 = u2f2(agent_ld_u64(dp + 3));
                    float4 wa4 = *(const float4*)(W_full + lane * 8);
                    float4 wb4 = *(const float4*)(W_full + lane * 8 + 4);
                    h2 e0 = u2h2(ev.x), e1 = u2h2(ev.y), e2 = u2h2(ev.z), e3 = u2h2(ev.w);
                    float a = 0.f;
                    a += fmaxf((float)e0.x + d0.x, 0.f) * wa4.x;
                    a += fmaxf((float)e0.y + d0.y, 0.f) * wa4.y;
                    a += fmaxf((float)e1.x + d1.x, 0.f) * wa4.z;
                    a += fmaxf((float)e1.y + d1.y, 0.f) * wa4.w;
                    a += fmaxf((float)e2.x + d2.x, 0.f) * wb4.x;
                    a += fmaxf((float)e2.y + d2.y, 0.f) * wb4.y;
                    a += fmaxf((float)e3.x + d3.x, 0.f) * wb4.z;
                    a += fmaxf((float)e3.y + d3.y, 0.f) * wb4.w;
                    for (int m = 32; m; m >>= 1) a += __shfl_xor(a, m);
                    if (lane == 0) agent_st_f(score + idx, a);
                }
            }
        }
        gbar(arrive, release, ep + 2u);

        // ---- Phase D: softmax + awe + build xh = [e_t | gate*awe | h] ----
        {
            int b = bid >> 3, cc = bid & 7, c0 = cc * 64;
            float* score_s = sm;
            float* alpha_s = sm + 200;
            float* part_s = sm + 400;
            if (t < 196) score_s[t] = agent_ld_f(score + b * 196 + t);
            __syncthreads();
            if (w == 0) {
                float v[4], e[4];
                float m = -1e30f;
                for (int i = 0; i < 4; ++i) {
                    int p = lane + i * 64;
                    v[i] = (p < 196) ? score_s[p] : -1e30f;
                    m = fmaxf(m, v[i]);
                }
                for (int mm = 32; mm; mm >>= 1) m = fmaxf(m, __shfl_xor(m, mm));
                float s = 0.f;
                for (int i = 0; i < 4; ++i) {
                    int p = lane + i * 64;
                    e[i] = (p < 196) ? expf(v[i] - m) : 0.f;
                    s += e[i];
                }
                for (int mm = 32; mm; mm >>= 1) s += __shfl_xor(s, mm);
                float inv = 1.0f / s;
                for (int i = 0; i < 4; ++i) {
                    int p = lane + i * 64;
                    if (p < 196) alpha_s[p] = e[i] * inv;
                }
            }
            __syncthreads();
            {
                int cx = t & 63, pg = t >> 6;
                float partial = 0.f;
                const f16* ep2 = enc_t + ((long)b * 196) * 512 + c0 + cx;
                for (int i = 0; i < 49; ++i) {
                    int p = pg * 49 + i;
                    partial += alpha_s[p] * (float)ep2[(long)p * 512];
                }
                part_s[pg * 64 + cx] = partial;
            }
            __syncthreads();
            if (t < 32) {
                int ca = c0 + 2 * t;
                float awe0 = part_s[2 * t] + part_s[64 + 2 * t] + part_s[128 + 2 * t] + part_s[192 + 2 * t];
                float awe1 = part_s[2 * t + 1] + part_s[64 + 2 * t + 1] + part_s[128 + 2 * t + 1] + part_s[192 + 2 * t + 1];
                float gp0 = agent_ld_f(da_gp + (long)b * 1024 + 512 + ca);
                float gp1 = agent_ld_f(da_gp + (long)b * 1024 + 512 + ca + 1);
                float g0 = sigf(gp0), g1 = sigf(gp1);
                int tok = caps[b * 64 + step];
                float e0 = emb[(long)tok * 512 + ca];
                float e1 = emb[(long)tok * 512 + ca + 1];
                unsigned* xp = (unsigned*)(xh + (long)b * 1536);
                int ci = (c0 >> 1) + t;
                h2 pe; pe.x = (f16)e0; pe.y = (f16)e1;
                agent_st_u(xp + ci, h22u(pe));
                h2 pa; pa.x = (f16)(g0 * awe0); pa.y = (f16)(g1 * awe1);
                agent_st_u(xp + 256 + ci, h22u(pa));
                unsigned hv = agent_ld_u((const unsigned*)(h_h + (long)b * 512) + ci);
                agent_st_u(xp + 512 + ci, hv);
            }
        }
        gbar(arrive, release, ep + 3u);

        // ---- Phase E: gates = xh @ Wcat + b ; LSTM pointwise ----
        {
            int bh = bid & 1, nc = bid >> 1;    // nc 0..127 -> j0 = nc*4
            int nl = t & 15, bl = t >> 4;
            int b = bh * 16 + bl;
            int n = (nl & 3) * 512 + nc * 4 + (nl >> 2);   // natural column index
            const f16* wp = Wcat8 + (long)n * 8;
            const unsigned* xp = (const unsigned*)(xh + (long)b * 1536);
            float acc0 = 0.f, acc1 = 0.f;
            for (int k8 = 0; k8 < 192; k8 += 2) {
                uint4 wa = *(const uint4*)(wp + (long)k8 * 16384);
                uint4 wb = *(const uint4*)(wp + ((long)k8 + 1) * 16384);
                unsigned x0 = agent_ld_u(xp + k8 * 4 + 0);
                unsigned x1 = agent_ld_u(xp + k8 * 4 + 1);
                unsigned x2 = agent_ld_u(xp + k8 * 4 + 2);
                unsigned x3 = agent_ld_u(xp + k8 * 4 + 3);
                unsigned x4 = agent_ld_u(xp + k8 * 4 + 4);
                unsigned x5 = agent_ld_u(xp + k8 * 4 + 5);
                unsigned x6 = agent_ld_u(xp + k8 * 4 + 6);
                unsigned x7 = agent_ld_u(xp + k8 * 4 + 7);
                acc0 = fdot2(u2h2(x0), u2h2(wa.x), acc0);
                acc0 = fdot2(u2h2(x1), u2h2(wa.y), acc0);
                acc0 = fdot2(u2h2(x2), u2h2(wa.z), acc0);
                acc0 = fdot2(u2h2(x3), u2h2(wa.w), acc0);
                acc1 = fdot2(u2h2(x4), u2h2(wb.x), acc1);
                acc1 = fdot2(u2h2(x5), u2h2(wb.y), acc1);
                acc1 = fdot2(u2h2(x6), u2h2(wb.z), acc1);
                acc1 = fdot2(u2h2(x7), u2h2(wb.w), acc1);
            }
            sm[bl * 16 + nl] = acc0 + acc1 + b_cat[n];
            __syncthreads();
            if (t < 32) {
                int bl2 = t >> 1, jp = t & 1;
                int b2 = bh * 16 + bl2;
                int j0 = nc * 4, jbase = j0 + jp * 2;
                unsigned* hhp = (unsigned*)(h_h + (long)b2 * 512) + (jbase >> 1);
                h2 oldh = u2h2(agent_ld_u(hhp));
                bool act = step < (cl[b2] - 1);
                h2 outp;
                for (int q = 0; q < 2; ++q) {
                    int jj = jp * 2 + q, j = j0 + jj;
                    float gi = sm[bl2 * 16 + jj * 4 + 0];
                    float gf = sm[bl2 * 16 + jj * 4 + 1];
                    float gg = sm[bl2 * 16 + jj * 4 + 2];
                    float go = sm[bl2 * 16 + jj * 4 + 3];
                    float cold = c[(long)b2 * 512 + j];
                    float cn = sigf(gf) * cold + sigf(gi) * tanhf(gg);
                    float hn = sigf(go) * tanhf(cn);
                    float hv, cv;
                    if (act) { hv = hn; cv = cn; }
                    else { hv = (float)(q ? oldh.y : oldh.x); cv = cold; }
                    c[(long)b2 * 512 + j] = cv;
                    if (q) outp.y = (f16)hv; else outp.x = (f16)hv;
                }
                unsigned pv = h22u(outp);
                agent_st_u(hhp, pv);
                *(unsigned*)(h_all + ((long)b2 * 63 + step) * 512 + jbase) = pv;
            }
            __syncthreads();
        }
        gbar(arrive, release, ep + 4u);
    }
}

// ---------------- launcher ----------------
extern "C" void kernel_launch(void* const* d_in, const int* in_sizes, int n_in,
                              void* d_out, int out_size, void* d_ws, size_t ws_size,
                              hipStream_t stream) {
    const float* encoder_out = (const float*)d_in[0];
    const int* caps = (const int*)d_in[1];
    const int* cl = (const int*)d_in[2];
    const float* emb = (const float*)d_in[3];
    const float* W_enc_att = (const float*)d_in[4];
    const float* b_enc_att = (const float*)d_in[5];
    const float* W_dec_att = (const float*)d_in[6];
    const float* b_dec_att = (const float*)d_in[7];
    const float* W_full_att = (const float*)d_in[8];
    const float* W_init_h = (const float*)d_in[10];
    const float* b_init_h = (const float*)d_in[11];
    const float* W_init_c = (const float*)d_in[12];
    const float* b_init_c = (const float*)d_in[13];
    const float* W_f_beta = (const float*)d_in[14];
    const float* b_f_beta = (const float*)d_in[15];
    const float* W_ih = (const float*)d_in[16];
    const float* b_ih = (const float*)d_in[17];
    const float* W_hh = (const float*)d_in[18];
    const float* b_hh = (const float*)d_in[19];
    const float* W_fc = (const float*)d_in[20];
    const float* b_fc = (const float*)d_in[21];

    char* p = (char*)d_ws;
    auto take = [&](size_t bytes) {
        char* r = p;
        p += (bytes + 255) & ~(size_t)255;
        return r;
    };
    f16* enc_t     = (f16*)take((size_t)32 * 196 * 512 * 2);
    f16* enc_att_h = (f16*)take((size_t)32 * 196 * 512 * 2);
    f16* W_encT    = (f16*)take((size_t)512 * 512 * 2);
    f16* W_fcT     = (f16*)take((size_t)10112 * 512 * 2);
    f16* Wdf8      = (f16*)take((size_t)512 * 1024 * 2);
    f16* Wcat8     = (f16*)take((size_t)1536 * 2048 * 2);
    f16* h_all     = (f16*)take((size_t)2048 * 512 * 2);
    f16* h_h       = (f16*)take((size_t)32 * 512 * 2);
    f16* xh        = (f16*)take((size_t)32 * 1536 * 2);
    float* b_df    = (float*)take(1024 * 4);
    float* b_cat   = (float*)take(2048 * 4);
    float* mean_e  = (float*)take((size_t)32 * 512 * 4);
    float* c_st    = (float*)take((size_t)32 * 512 * 4);
    float* da_gp   = (float*)take((size_t)32 * 1024 * 4);
    float* score   = (float*)take((size_t)32 * 196 * 4);
    unsigned* bar  = (unsigned*)take(2048);

    k_prep_w<<<1024, 256, 0, stream>>>(W_enc_att, W_dec_att, W_f_beta,
                                       b_dec_att, b_f_beta, b_ih, b_hh,
                                       W_encT, Wdf8, b_df, b_cat);
    k_tr_fc<<<dim3(158, 8), 256, 0, stream>>>(W_fc, W_fcT);
    k_pack_cat<<<dim3(24, 32), 256, 0, stream>>>(W_ih, W_hh, Wcat8);
    k_prep_enc<<<256, 256, 0, stream>>>(encoder_out, enc_t, mean_e);
    k_h0c0<<<65, 256, 0, stream>>>(mean_e, W_init_h, b_init_h, W_init_c, b_init_c,
                                   c_st, h_h, h_all, bar);
    k_encatt<<<dim3(49, 4), 256, 0, stream>>>(enc_t, W_encT, b_enc_att, enc_att_h);
    k_loop<<<256, 256, 0, stream>>>(Wdf8, b_df, Wcat8, b_cat, enc_att_h, enc_t,
                                    W_full_att, emb, caps, cl,
                                    c_st, h_h, da_gp, score, xh, h_all, bar);
    k_fc<<<dim3(16, 79), 256, 0, stream>>>(h_all, W_fcT, b_fc, cl, (float*)d_out);
}

// Round 3
// 3962.409 us; speedup vs baseline: 2.1773x; 1.3426x over previous
//
#include <hip/hip_runtime.h>
#include <cstdint>
#include <cstddef>

// ---------------- problem constants ----------------
// B=32, ENC=512, P=196 (14x14), ATT=512, EMB=512, DEC=512, VOCAB=10000, T=63
typedef _Float16 f16;
typedef _Float16 h2 __attribute__((ext_vector_type(2)));
typedef _Float16 h8 __attribute__((ext_vector_type(8)));
typedef float f4v __attribute__((ext_vector_type(4)));

// ---------------- helpers ----------------
__device__ __forceinline__ h2 u2h2(unsigned u) { return __builtin_bit_cast(h2, u); }
__device__ __forceinline__ unsigned h22u(h2 v) { return __builtin_bit_cast(unsigned, v); }
__device__ __forceinline__ float2 u2f2(unsigned long long u) { return __builtin_bit_cast(float2, u); }

__device__ __forceinline__ float agent_ld_f(const float* p) {
    return __hip_atomic_load(p, __ATOMIC_RELAXED, __HIP_MEMORY_SCOPE_AGENT);
}
__device__ __forceinline__ void agent_st_f(float* p, float v) {
    __hip_atomic_store(p, v, __ATOMIC_RELAXED, __HIP_MEMORY_SCOPE_AGENT);
}
__device__ __forceinline__ unsigned agent_ld_u(const unsigned* p) {
    return __hip_atomic_load(p, __ATOMIC_RELAXED, __HIP_MEMORY_SCOPE_AGENT);
}
__device__ __forceinline__ void agent_st_u(unsigned* p, unsigned v) {
    __hip_atomic_store(p, v, __ATOMIC_RELAXED, __HIP_MEMORY_SCOPE_AGENT);
}
__device__ __forceinline__ unsigned long long agent_ld_u64(const unsigned long long* p) {
    return __hip_atomic_load(p, __ATOMIC_RELAXED, __HIP_MEMORY_SCOPE_AGENT);
}

__device__ __forceinline__ float fdot2(h2 a, h2 b, float c) {
#if __has_builtin(__builtin_amdgcn_fdot2)
    return __builtin_amdgcn_fdot2(a, b, c, false);
#else
    return c + (float)a.x * (float)b.x + (float)a.y * (float)b.y;
#endif
}
__device__ __forceinline__ float sigf(float x) { return 1.0f / (1.0f + expf(-x)); }

// grid barrier: ALL-RELAXED atomics + compiler-only ordering.
// Rationale: every cross-block datum (h_h, da_gp, score, xh) is accessed via
// agent-scope atomics which bypass the non-coherent per-XCD L2 and are served
// at the LLC coherence point. __syncthreads() already drains vmcnt(0) per wave
// before s_barrier, so all agent stores are LLC-visible before the arrive
// store. Using RELEASE/ACQUIRE here would emit buffer_wbl2/buffer_inv, which
// wipes the L2-resident weight streams every barrier (measured: 20 MB/step
// refetch, 1.28 GB FETCH_SIZE). Relaxed-only keeps L2 hot.
__device__ __forceinline__ void gbar(unsigned* arrive, unsigned* release, unsigned epoch) {
    __syncthreads();    // emits s_waitcnt vmcnt(0) lgkmcnt(0); s_barrier (per wave)
    if (blockIdx.x == 0) {
        if (threadIdx.x < 64) {
            int l = threadIdx.x;
            if (l == 0) {
                asm volatile("s_waitcnt vmcnt(0)" ::: "memory");
                __hip_atomic_store(&arrive[0], epoch, __ATOMIC_RELAXED, __HIP_MEMORY_SCOPE_AGENT);
            }
            bool ok;
            do {
                ok = true;
#pragma unroll
                for (int i = 0; i < 4; ++i)
                    ok = ok && (__hip_atomic_load(&arrive[l + i * 64], __ATOMIC_RELAXED,
                                                  __HIP_MEMORY_SCOPE_AGENT) == epoch);
                if (!ok) __builtin_amdgcn_s_sleep(1);
            } while (__ballot(ok) != ~0ull);
            asm volatile("" ::: "memory");
            if (l == 0)
                __hip_atomic_store(release, epoch, __ATOMIC_RELAXED, __HIP_MEMORY_SCOPE_AGENT);
        }
    } else {
        if (threadIdx.x == 0) {
            asm volatile("s_waitcnt vmcnt(0)" ::: "memory");
            __hip_atomic_store(&arrive[blockIdx.x], epoch, __ATOMIC_RELAXED, __HIP_MEMORY_SCOPE_AGENT);
            while (__hip_atomic_load(release, __ATOMIC_RELAXED, __HIP_MEMORY_SCOPE_AGENT) != epoch)
                __builtin_amdgcn_s_sleep(1);
            asm volatile("" ::: "memory");
        }
    }
    __syncthreads();
}

// ---------------- prep: small weights / biases ----------------
// W_encT[n][k] fp16 ; Wdf8 k8-packed cols [dec_att 512 | f_beta 512]
// b_df = [b_dec | b_fb] ; b_cat[n] = b_ih[n] + b_hh[n] (natural order)
__global__ void k_prep_w(const float* W_enc, const float* W_dec, const float* W_fb,
                         const float* b_dec, const float* b_fb,
                         const float* b_ih, const float* b_hh,
                         f16* W_encT, f16* Wdf8, float* b_df, float* b_cat) {
    const int S0 = 512 * 512;
    const int S2 = 512 * 1024;
    const int total = S0 + S2 + 1024 + 2048;
    for (int idx = blockIdx.x * 256 + threadIdx.x; idx < total; idx += gridDim.x * 256) {
        int i = idx;
        if (i < S0) { int n = i >> 9, k = i & 511; W_encT[i] = (f16)W_enc[k * 512 + n]; continue; }
        i -= S0;
        if (i < S2) {
            int k8 = i / 8192, r = i % 8192, col = r >> 3, kr = r & 7;
            int k = k8 * 8 + kr;
            float v = (col < 512) ? W_dec[k * 512 + col] : W_fb[k * 512 + (col - 512)];
            Wdf8[i] = (f16)v;
            continue;
        }
        i -= S2;
        if (i < 1024) { b_df[i] = (i < 512) ? b_dec[i] : b_fb[i - 512]; continue; }
        i -= 1024;
        b_cat[i] = b_ih[i] + b_hh[i];
    }
}

// ---------------- prep: tiled transpose W_fc -> W_fcT[n][k] fp16 ----------------
__global__ void k_tr_fc(const float* W_fc, f16* W_fcT) {
    __shared__ float tile[64][65];
    int n0 = blockIdx.x * 64;   // 158 tiles -> 10112 (zero-pad past 10000)
    int k0 = blockIdx.y * 64;   // 8 tiles
    int t = threadIdx.x;
#pragma unroll
    for (int i = 0; i < 16; ++i) {
        int lin = t + i * 256;
        int kl = lin >> 6, nl = lin & 63;
        int n = n0 + nl;
        tile[kl][nl] = (n < 10000) ? W_fc[(long)(k0 + kl) * 10000 + n] : 0.0f;
    }
    __syncthreads();
#pragma unroll
    for (int i = 0; i < 2; ++i) {
        int lin = t + i * 256;          // 512 = 64 rows x 8 vec-cols
        int r = lin >> 3, cv = lin & 7;
        f16 v[8];
#pragma unroll
        for (int kr = 0; kr < 8; ++kr) v[kr] = (f16)tile[cv * 8 + kr][r];
        *(uint4*)&W_fcT[(long)(n0 + r) * 512 + k0 + cv * 8] = *(uint4*)v;
    }
}

// ---------------- prep: tiled k8-repack [W_ih;W_hh] -> Wcat8[k8][n][kr] ----------------
__global__ void k_pack_cat(const float* W_ih, const float* W_hh, f16* Wcat8) {
    __shared__ float tile[64][65];
    int k0 = blockIdx.x * 64;   // 24 tiles (K=1536)
    int n0 = blockIdx.y * 64;   // 32 tiles (N=2048)
    int t = threadIdx.x;
#pragma unroll
    for (int i = 0; i < 16; ++i) {
        int lin = t + i * 256;
        int kl = lin >> 6, nl = lin & 63;
        int k = k0 + kl;
        float v = (k < 1024) ? W_ih[(long)k * 2048 + n0 + nl]
                             : W_hh[(long)(k - 1024) * 2048 + n0 + nl];
        tile[kl][nl] = v;
    }
    __syncthreads();
#pragma unroll
    for (int i = 0; i < 2; ++i) {
        int lin = t + i * 256;          // 512 = 8 k8 x 64 n
        int nl = lin & 63, k8l = lin >> 6;
        f16 v[8];
#pragma unroll
        for (int kr = 0; kr < 8; ++kr) v[kr] = (f16)tile[k8l * 8 + kr][nl];
        *(uint4*)&Wcat8[(long)(k0 / 8 + k8l) * 16384 + (long)(n0 + nl) * 8] = *(uint4*)v;
    }
}

// ---------------- prep: enc transpose + mean ----------------
__global__ void k_prep_enc(const float* enc_out, f16* enc_t, float* mean_enc) {
    __shared__ float tile[64][197];
    int b = blockIdx.x >> 3, cc = blockIdx.x & 7, c0 = cc * 64;
    int t = threadIdx.x;
    const float* src = enc_out + ((long)b * 512 + c0) * 196;
    for (int i = 0; i < 49; ++i) {
        int lin = t + i * 256;          // 0..12543 = 64*196
        int cl = lin / 196, p = lin % 196;
        tile[cl][p] = src[cl * 196 + p];
    }
    __syncthreads();
    if (t < 64) {
        float s = 0.f;
        for (int p = 0; p < 196; ++p) s += tile[t][p];
        mean_enc[b * 512 + c0 + t] = s * (1.0f / 196.0f);
    }
    __syncthreads();
    int cl = t & 63, pg = t >> 6;
    for (int i = 0; i < 49; ++i) {
        int p = pg * 49 + i;
        enc_t[((long)(b * 196 + p)) * 512 + c0 + cl] = (f16)tile[cl][p];
    }
}

// ---------------- h0/c0 + barrier/tail init ----------------
__global__ void k_h0c0(const float* mean_enc, const float* W_init_h, const float* b_init_h,
                       const float* W_init_c, const float* b_init_c,
                       float* c, f16* h_h, f16* h_all, unsigned* bar) {
    if (blockIdx.x == 64) {
        int t = threadIdx.x;
        for (int i = t; i < 512; i += 256) bar[i] = 0u;
        for (int i = t; i < 32 * 512; i += 256) h_all[(long)2016 * 512 + i] = (f16)0.0f;
        return;
    }
    __shared__ float ms[512];
    int b = blockIdx.x >> 1, which = blockIdx.x & 1;
    const float* W = which ? W_init_c : W_init_h;
    const float* bb = which ? b_init_c : b_init_h;
    int t = threadIdx.x;
    ms[t] = mean_enc[b * 512 + t];
    ms[t + 256] = mean_enc[b * 512 + t + 256];
    __syncthreads();
    for (int jj = 0; jj < 2; ++jj) {
        int j = t + jj * 256;
        float acc = bb[j];
        for (int k = 0; k < 512; ++k) acc += ms[k] * W[k * 512 + j];
        if (which) c[b * 512 + j] = acc;
        else h_h[b * 512 + j] = (f16)acc;
    }
}

// ---------------- enc_att = enc @ W_enc_att + b (fp16 MFMA) ----------------
__global__ __launch_bounds__(256, 2) void k_encatt(const f16* A, const f16* Bt,
                                                   const float* bias, f16* Cout) {
    __shared__ __align__(16) f16 As[128 * 32];
    __shared__ __align__(16) f16 Bs[128 * 32];
    int m0 = blockIdx.x * 128, n0 = blockIdx.y * 128;
    int t = threadIdx.x, w = t >> 6, lane = t & 63;
    int wm = (w >> 1) * 64, wn = (w & 1) * 64;
    int lm = lane & 15, lq = lane >> 4;
    f4v acc[4][4];
    for (int mi = 0; mi < 4; ++mi)
        for (int ni = 0; ni < 4; ++ni) acc[mi][ni] = (f4v){0.f, 0.f, 0.f, 0.f};
    for (int kb = 0; kb < 512; kb += 32) {
        for (int i = 0; i < 2; ++i) {
            int li = t + i * 256;
            int row = li >> 2, q = li & 3;
            *(uint4*)&As[row * 32 + q * 8] = *(const uint4*)&A[(long)(m0 + row) * 512 + kb + q * 8];
            *(uint4*)&Bs[row * 32 + q * 8] = *(const uint4*)&Bt[(long)(n0 + row) * 512 + kb + q * 8];
        }
        __syncthreads();
        h8 af[4], bf[4];
        for (int i = 0; i < 4; ++i) {
            af[i] = *(const h8*)&As[(wm + i * 16 + lm) * 32 + lq * 8];
            bf[i] = *(const h8*)&Bs[(wn + i * 16 + lm) * 32 + lq * 8];
        }
        for (int mi = 0; mi < 4; ++mi)
            for (int ni = 0; ni < 4; ++ni)
                acc[mi][ni] = __builtin_amdgcn_mfma_f32_16x16x32_f16(af[mi], bf[ni], acc[mi][ni], 0, 0, 0);
        __syncthreads();
    }
    for (int mi = 0; mi < 4; ++mi)
        for (int ni = 0; ni < 4; ++ni)
            for (int r = 0; r < 4; ++r) {
                int row = m0 + wm + mi * 16 + lq * 4 + r;
                int col = n0 + wn + ni * 16 + lm;
                Cout[(long)row * 512 + col] = (f16)(acc[mi][ni][r] + bias[col]);
            }
}

// ---------------- final FC: preds = h_all @ W_fc + b_fc (fp16 MFMA, masked) ----------------
__global__ __launch_bounds__(256, 2) void k_fc(const f16* A, const f16* Bt, const float* bias,
                                               const int* cl, float* out) {
    __shared__ __align__(16) f16 As[128 * 32];
    __shared__ __align__(16) f16 Bs[128 * 32];
    int m0 = blockIdx.x * 128, n0 = blockIdx.y * 128;
    int t = threadIdx.x, w = t >> 6, lane = t & 63;
    int wm = (w >> 1) * 64, wn = (w & 1) * 64;
    int lm = lane & 15, lq = lane >> 4;

    bool myact = false;
    if (t < 128) {
        int row = m0 + t;
        if (row < 2016) {
            int b = row / 63, tt = row - b * 63;
            myact = tt < (cl[b] - 1);
        }
    }
    int anyact = __syncthreads_or((int)myact);
    if (!anyact) {
        for (int i = 0; i < 64; ++i) {
            int idx = t + i * 256;
            int row = m0 + (idx >> 7), col = n0 + (idx & 127);
            if (row < 2016 && col < 10000) out[(long)row * 10000 + col] = 0.0f;
        }
        return;
    }

    f4v acc[4][4];
    for (int mi = 0; mi < 4; ++mi)
        for (int ni = 0; ni < 4; ++ni) acc[mi][ni] = (f4v){0.f, 0.f, 0.f, 0.f};
    for (int kb = 0; kb < 512; kb += 32) {
        for (int i = 0; i < 2; ++i) {
            int li = t + i * 256;
            int row = li >> 2, q = li & 3;
            *(uint4*)&As[row * 32 + q * 8] = *(const uint4*)&A[(long)(m0 + row) * 512 + kb + q * 8];
            *(uint4*)&Bs[row * 32 + q * 8] = *(const uint4*)&Bt[(long)(n0 + row) * 512 + kb + q * 8];
        }
        __syncthreads();
        h8 af[4], bf[4];
        for (int i = 0; i < 4; ++i) {
            af[i] = *(const h8*)&As[(wm + i * 16 + lm) * 32 + lq * 8];
            bf[i] = *(const h8*)&Bs[(wn + i * 16 + lm) * 32 + lq * 8];
        }
        for (int mi = 0; mi < 4; ++mi)
            for (int ni = 0; ni < 4; ++ni)
                acc[mi][ni] = __builtin_amdgcn_mfma_f32_16x16x32_f16(af[mi], bf[ni], acc[mi][ni], 0, 0, 0);
        __syncthreads();
    }
    for (int mi = 0; mi < 4; ++mi)
        for (int ni = 0; ni < 4; ++ni)
            for (int r = 0; r < 4; ++r) {
                int row = m0 + wm + mi * 16 + lq * 4 + r;
                int col = n0 + wn + ni * 16 + lm;
                if (row < 2016 && col < 10000) {
                    int b = row / 63, tt = row - b * 63;
                    bool act = tt < (cl[b] - 1);
                    out[(long)row * 10000 + col] = act ? (acc[mi][ni][r] + bias[col]) : 0.0f;
                }
            }
}

// ---------------- persistent recurrent loop ----------------
// 256 blocks x 256 threads, 63 steps, 4 grid barriers/step.
__global__ __launch_bounds__(256, 2) void k_loop(
    const f16* Wdf8, const float* b_df,
    const f16* Wcat8, const float* b_cat,
    const f16* enc_att_h, const f16* enc_t,
    const float* W_full, const float* emb, const int* caps, const int* cl,
    float* c, f16* h_h, float* da_gp, float* score, f16* xh, f16* h_all,
    unsigned* bar) {
    __shared__ float sm[768];
    const int bid = blockIdx.x, t = threadIdx.x;
    const int lane = t & 63, w = t >> 6;
    unsigned* arrive = bar;
    unsigned* release = bar + 384;

    for (int step = 0; step < 63; ++step) {
        unsigned ep = (unsigned)step * 4u;
        // ---- Phase A: dec_a / gate_pre = h @ [W_dec_att | W_f_beta] + b ----
        if (bid < 128) {
            int cc = bid & 15, bq = bid >> 4;
            int col = cc * 64 + lane;
            int b = bq * 4 + w;
            const f16* wp = Wdf8 + (long)col * 8;
            const unsigned* hp = (const unsigned*)(h_h + (long)b * 512);
            float acc0 = 0.f, acc1 = 0.f;
            for (int k8 = 0; k8 < 64; k8 += 2) {
                uint4 wa = *(const uint4*)(wp + (long)k8 * 8192);
                uint4 wb = *(const uint4*)(wp + ((long)k8 + 1) * 8192);
                unsigned x0 = agent_ld_u(hp + k8 * 4 + 0);
                unsigned x1 = agent_ld_u(hp + k8 * 4 + 1);
                unsigned x2 = agent_ld_u(hp + k8 * 4 + 2);
                unsigned x3 = agent_ld_u(hp + k8 * 4 + 3);
                unsigned x4 = agent_ld_u(hp + k8 * 4 + 4);
                unsigned x5 = agent_ld_u(hp + k8 * 4 + 5);
                unsigned x6 = agent_ld_u(hp + k8 * 4 + 6);
                unsigned x7 = agent_ld_u(hp + k8 * 4 + 7);
                acc0 = fdot2(u2h2(x0), u2h2(wa.x), acc0);
                acc0 = fdot2(u2h2(x1), u2h2(wa.y), acc0);
                acc0 = fdot2(u2h2(x2), u2h2(wa.z), acc0);
                acc0 = fdot2(u2h2(x3), u2h2(wa.w), acc0);
                acc1 = fdot2(u2h2(x4), u2h2(wb.x), acc1);
                acc1 = fdot2(u2h2(x5), u2h2(wb.y), acc1);
                acc1 = fdot2(u2h2(x6), u2h2(wb.z), acc1);
                acc1 = fdot2(u2h2(x7), u2h2(wb.w), acc1);
            }
            agent_st_f(da_gp + (long)b * 1024 + col, acc0 + acc1 + b_df[col]);
        }
        gbar(arrive, release, ep + 1u);

        // ---- Phase B: score = relu(enc_att + dec_a) . W_full ----
        {
            int gw = bid * 4 + w;
            for (int r = 0; r < 7; ++r) {
                int idx = gw + r * 1024;
                if (idx < 6272) {
                    int b = idx / 196;
                    uint4 ev = *(const uint4*)(enc_att_h + (long)idx * 512 + lane * 8);
                    const unsigned long long* dp =
                        (const unsigned long long*)(da_gp + (long)b * 1024 + lane * 8);
                    float2 d0 = u2f2(agent_ld_u64(dp + 0));
                    float2 d1 = u2f2(agent_ld_u64(dp + 1));
                    float2 d2 = u2f2(agent_ld_u64(dp + 2));
                    float2 d3 = u2f2(agent_ld_u64(dp + 3));
                    float4 wa4 = *(const float4*)(W_full + lane * 8);
                    float4 wb4 = *(const float4*)(W_full + lane * 8 + 4);
                    h2 e0 = u2h2(ev.x), e1 = u2h2(ev.y), e2 = u2h2(ev.z), e3 = u2h2(ev.w);
                    float a = 0.f;
                    a += fmaxf((float)e0.x + d0.x, 0.f) * wa4.x;
                    a += fmaxf((float)e0.y + d0.y, 0.f) * wa4.y;
                    a += fmaxf((float)e1.x + d1.x, 0.f) * wa4.z;
                    a += fmaxf((float)e1.y + d1.y, 0.f) * wa4.w;
                    a += fmaxf((float)e2.x + d2.x, 0.f) * wb4.x;
                    a += fmaxf((float)e2.y + d2.y, 0.f) * wb4.y;
                    a += fmaxf((float)e3.x + d3.x, 0.f) * wb4.z;
                    a += fmaxf((float)e3.y + d3.y, 0.f) * wb4.w;
                    for (int m = 32; m; m >>= 1) a += __shfl_xor(a, m);
                    if (lane == 0) agent_st_f(score + idx, a);
                }
            }
        }
        gbar(arrive, release, ep + 2u);

        // ---- Phase D: softmax + awe + build xh = [e_t | gate*awe | h] ----
        {
            int b = bid >> 3, cc = bid & 7, c0 = cc * 64;
            float* score_s = sm;
            float* alpha_s = sm + 200;
            float* part_s = sm + 400;
            if (t < 196) score_s[t] = agent_ld_f(score + b * 196 + t);
            __syncthreads();
            if (w == 0) {
                float v[4], e[4];
                float m = -1e30f;
                for (int i = 0; i < 4; ++i) {
                    int p = lane + i * 64;
                    v[i] = (p < 196) ? score_s[p] : -1e30f;
                    m = fmaxf(m, v[i]);
                }
                for (int mm = 32; mm; mm >>= 1) m = fmaxf(m, __shfl_xor(m, mm));
                float s = 0.f;
                for (int i = 0; i < 4; ++i) {
                    int p = lane + i * 64;
                    e[i] = (p < 196) ? expf(v[i] - m) : 0.f;
                    s += e[i];
                }
                for (int mm = 32; mm; mm >>= 1) s += __shfl_xor(s, mm);
                float inv = 1.0f / s;
                for (int i = 0; i < 4; ++i) {
                    int p = lane + i * 64;
                    if (p < 196) alpha_s[p] = e[i] * inv;
                }
            }
            __syncthreads();
            {
                int cx = t & 63, pg = t >> 6;
                float partial = 0.f;
                const f16* ep2 = enc_t + ((long)b * 196) * 512 + c0 + cx;
                for (int i = 0; i < 49; ++i) {
                    int p = pg * 49 + i;
                    partial += alpha_s[p] * (float)ep2[(long)p * 512];
                }
                part_s[pg * 64 + cx] = partial;
            }
            __syncthreads();
            if (t < 32) {
                int ca = c0 + 2 * t;
                float awe0 = part_s[2 * t] + part_s[64 + 2 * t] + part_s[128 + 2 * t] + part_s[192 + 2 * t];
                float awe1 = part_s[2 * t + 1] + part_s[64 + 2 * t + 1] + part_s[128 + 2 * t + 1] + part_s[192 + 2 * t + 1];
                float gp0 = agent_ld_f(da_gp + (long)b * 1024 + 512 + ca);
                float gp1 = agent_ld_f(da_gp + (long)b * 1024 + 512 + ca + 1);
                float g0 = sigf(gp0), g1 = sigf(gp1);
                int tok = caps[b * 64 + step];
                float e0 = emb[(long)tok * 512 + ca];
                float e1 = emb[(long)tok * 512 + ca + 1];
                unsigned* xp = (unsigned*)(xh + (long)b * 1536);
                int ci = (c0 >> 1) + t;
                h2 pe; pe.x = (f16)e0; pe.y = (f16)e1;
                agent_st_u(xp + ci, h22u(pe));
                h2 pa; pa.x = (f16)(g0 * awe0); pa.y = (f16)(g1 * awe1);
                agent_st_u(xp + 256 + ci, h22u(pa));
                unsigned hv = agent_ld_u((const unsigned*)(h_h + (long)b * 512) + ci);
                agent_st_u(xp + 512 + ci, hv);
            }
        }
        gbar(arrive, release, ep + 3u);

        // ---- Phase E: gates = xh @ Wcat + b ; LSTM pointwise ----
        {
            int bh = bid & 1, nc = bid >> 1;    // nc 0..127 -> j0 = nc*4
            int nl = t & 15, bl = t >> 4;
            int b = bh * 16 + bl;
            int n = (nl & 3) * 512 + nc * 4 + (nl >> 2);   // natural column index
            const f16* wp = Wcat8 + (long)n * 8;
            const unsigned* xp = (const unsigned*)(xh + (long)b * 1536);
            float acc0 = 0.f, acc1 = 0.f;
            for (int k8 = 0; k8 < 192; k8 += 2) {
                uint4 wa = *(const uint4*)(wp + (long)k8 * 16384);
                uint4 wb = *(const uint4*)(wp + ((long)k8 + 1) * 16384);
                unsigned x0 = agent_ld_u(xp + k8 * 4 + 0);
                unsigned x1 = agent_ld_u(xp + k8 * 4 + 1);
                unsigned x2 = agent_ld_u(xp + k8 * 4 + 2);
                unsigned x3 = agent_ld_u(xp + k8 * 4 + 3);
                unsigned x4 = agent_ld_u(xp + k8 * 4 + 4);
                unsigned x5 = agent_ld_u(xp + k8 * 4 + 5);
                unsigned x6 = agent_ld_u(xp + k8 * 4 + 6);
                unsigned x7 = agent_ld_u(xp + k8 * 4 + 7);
                acc0 = fdot2(u2h2(x0), u2h2(wa.x), acc0);
                acc0 = fdot2(u2h2(x1), u2h2(wa.y), acc0);
                acc0 = fdot2(u2h2(x2), u2h2(wa.z), acc0);
                acc0 = fdot2(u2h2(x3), u2h2(wa.w), acc0);
                acc1 = fdot2(u2h2(x4), u2h2(wb.x), acc1);
                acc1 = fdot2(u2h2(x5), u2h2(wb.y), acc1);
                acc1 = fdot2(u2h2(x6), u2h2(wb.z), acc1);
                acc1 = fdot2(u2h2(x7), u2h2(wb.w), acc1);
            }
            sm[bl * 16 + nl] = acc0 + acc1 + b_cat[n];
            __syncthreads();
            if (t < 32) {
                int bl2 = t >> 1, jp = t & 1;
                int b2 = bh * 16 + bl2;
                int j0 = nc * 4, jbase = j0 + jp * 2;
                unsigned* hhp = (unsigned*)(h_h + (long)b2 * 512) + (jbase >> 1);
                h2 oldh = u2h2(agent_ld_u(hhp));
                bool act = step < (cl[b2] - 1);
                h2 outp;
                for (int q = 0; q < 2; ++q) {
                    int jj = jp * 2 + q, j = j0 + jj;
                    float gi = sm[bl2 * 16 + jj * 4 + 0];
                    float gf = sm[bl2 * 16 + jj * 4 + 1];
                    float gg = sm[bl2 * 16 + jj * 4 + 2];
                    float go = sm[bl2 * 16 + jj * 4 + 3];
                    float cold = c[(long)b2 * 512 + j];
                    float cn = sigf(gf) * cold + sigf(gi) * tanhf(gg);
                    float hn = sigf(go) * tanhf(cn);
                    float hv, cv;
                    if (act) { hv = hn; cv = cn; }
                    else { hv = (float)(q ? oldh.y : oldh.x); cv = cold; }
                    c[(long)b2 * 512 + j] = cv;
                    if (q) outp.y = (f16)hv; else outp.x = (f16)hv;
                }
                unsigned pv = h22u(outp);
                agent_st_u(hhp, pv);
                *(unsigned*)(h_all + ((long)b2 * 63 + step) * 512 + jbase) = pv;
            }
            __syncthreads();
        }
        gbar(arrive, release, ep + 4u);
    }
}

// ---------------- launcher ----------------
extern "C" void kernel_launch(void* const* d_in, const int* in_sizes, int n_in,
                              void* d_out, int out_size, void* d_ws, size_t ws_size,
                              hipStream_t stream) {
    const float* encoder_out = (const float*)d_in[0];
    const int* caps = (const int*)d_in[1];
    const int* cl = (const int*)d_in[2];
    const float* emb = (const float*)d_in[3];
    const float* W_enc_att = (const float*)d_in[4];
    const float* b_enc_att = (const float*)d_in[5];
    const float* W_dec_att = (const float*)d_in[6];
    const float* b_dec_att = (const float*)d_in[7];
    const float* W_full_att = (const float*)d_in[8];
    const float* W_init_h = (const float*)d_in[10];
    const float* b_init_h = (const float*)d_in[11];
    const float* W_init_c = (const float*)d_in[12];
    const float* b_init_c = (const float*)d_in[13];
    const float* W_f_beta = (const float*)d_in[14];
    const float* b_f_beta = (const float*)d_in[15];
    const float* W_ih = (const float*)d_in[16];
    const float* b_ih = (const float*)d_in[17];
    const float* W_hh = (const float*)d_in[18];
    const float* b_hh = (const float*)d_in[19];
    const float* W_fc = (const float*)d_in[20];
    const float* b_fc = (const float*)d_in[21];

    char* p = (char*)d_ws;
    auto take = [&](size_t bytes) {
        char* r = p;
        p += (bytes + 255) & ~(size_t)255;
        return r;
    };
    f16* enc_t     = (f16*)take((size_t)32 * 196 * 512 * 2);
    f16* enc_att_h = (f16*)take((size_t)32 * 196 * 512 * 2);
    f16* W_encT    = (f16*)take((size_t)512 * 512 * 2);
    f16* W_fcT     = (f16*)take((size_t)10112 * 512 * 2);
    f16* Wdf8      = (f16*)take((size_t)512 * 1024 * 2);
    f16* Wcat8     = (f16*)take((size_t)1536 * 2048 * 2);
    f16* h_all     = (f16*)take((size_t)2048 * 512 * 2);
    f16* h_h       = (f16*)take((size_t)32 * 512 * 2);
    f16* xh        = (f16*)take((size_t)32 * 1536 * 2);
    float* b_df    = (float*)take(1024 * 4);
    float* b_cat   = (float*)take(2048 * 4);
    float* mean_e  = (float*)take((size_t)32 * 512 * 4);
    float* c_st    = (float*)take((size_t)32 * 512 * 4);
    float* da_gp   = (float*)take((size_t)32 * 1024 * 4);
    float* score   = (float*)take((size_t)32 * 196 * 4);
    unsigned* bar  = (unsigned*)take(2048);

    k_prep_w<<<1024, 256, 0, stream>>>(W_enc_att, W_dec_att, W_f_beta,
                                       b_dec_att, b_f_beta, b_ih, b_hh,
                                       W_encT, Wdf8, b_df, b_cat);
    k_tr_fc<<<dim3(158, 8), 256, 0, stream>>>(W_fc, W_fcT);
    k_pack_cat<<<dim3(24, 32), 256, 0, stream>>>(W_ih, W_hh, Wcat8);
    k_prep_enc<<<256, 256, 0, stream>>>(encoder_out, enc_t, mean_e);
    k_h0c0<<<65, 256, 0, stream>>>(mean_e, W_init_h, b_init_h, W_init_c, b_init_c,
                                   c_st, h_h, h_all, bar);
    k_encatt<<<dim3(49, 4), 256, 0, stream>>>(enc_t, W_encT, b_enc_att, enc_att_h);
    k_loop<<<256, 256, 0, stream>>>(Wdf8, b_df, Wcat8, b_cat, enc_att_h, enc_t,
                                    W_full_att, emb, caps, cl,
                                    c_st, h_h, da_gp, score, xh, h_all, bar);
    k_fc<<<dim3(16, 79), 256, 0, stream>>>(h_all, W_fcT, b_fc, cl, (float*)d_out);
}